// Round 11
// baseline (383.405 us; speedup 1.0000x reference)
//
#include <hip/hip_runtime.h>

typedef unsigned int u32;
typedef unsigned short u16;

#define T_SEQ 256
#define N_DIM 2048
#define D_DIM 128
#define B_BATCH 8

typedef __attribute__((ext_vector_type(8))) short bfrag;   // 8 bf16 (4 VGPRs)
typedef __attribute__((ext_vector_type(4))) float f4acc;   // 4 f32 acc

__device__ __forceinline__ u16 f2bf(float f) {  // RNE
  u32 u = __float_as_uint(f);
  return (u16)((u + 0x7FFFu + ((u >> 16) & 1u)) >> 16);
}
__device__ __forceinline__ float bf2f(u16 h) { return __uint_as_float(((u32)h) << 16); }

// async global->LDS, 16B per lane; LDS dst is wave-uniform base + lane*16 (HW)
__device__ __forceinline__ void stage16(const void* g, void* l) {
  __builtin_amdgcn_global_load_lds(
      (const __attribute__((address_space(1))) void*)g,
      (__attribute__((address_space(3))) void*)l, 16, 0, 0);
}

// ---------- gather: Vp[r,:] = token_emb[tokens[r]] (+ bf16 hi/lo) -------
__global__ __launch_bounds__(128) void k_gather(const float* __restrict__ emb,
                                                const int* __restrict__ toks,
                                                float* __restrict__ Vp,
                                                u16* __restrict__ Vph,
                                                u16* __restrict__ Vpl) {
  int r = blockIdx.x;
  int d = threadIdx.x;
  float v = emb[(long)toks[r] * D_DIM + d];
  long o = (long)r * D_DIM + d;
  Vp[o] = v;
  u16 h = f2bf(v);
  Vph[o] = h;
  Vpl[o] = f2bf(v - bf2f(h));
}

// ---------------- f32 -> bf16 cast (grid-stride) ------------------------
__global__ __launch_bounds__(256) void k_cast(const float* __restrict__ src,
                                              u16* __restrict__ dst, int n) {
  for (int i = blockIdx.x * 256 + threadIdx.x; i < n; i += gridDim.x * 256)
    dst[i] = f2bf(src[i]);
}

// ---------------- f32 -> bf16 hi/lo split cast --------------------------
__global__ __launch_bounds__(256) void k_cast2(const float* __restrict__ src,
                                               u16* __restrict__ h,
                                               u16* __restrict__ l, int n) {
  for (int i = blockIdx.x * 256 + threadIdx.x; i < n; i += gridDim.x * 256) {
    float v = src[i];
    u16 hh = f2bf(v);
    h[i] = hh;
    l[i] = f2bf(v - bf2f(hh));
  }
}

// ---------------- zero fill (float4 granular) ---------------------------
__global__ __launch_bounds__(256) void k_zero(float* __restrict__ p, long n4) {
  long i = (long)blockIdx.x * blockDim.x + threadIdx.x;
  if (i < n4) ((float4*)p)[i] = make_float4(0.f, 0.f, 0.f, 0.f);
}

// ------- P = Ah@Bh^T + Ah@Bl^T + Al@Bh^T (bf16x3 ~= f32 GEMM) -----------
// 64x64 tile, K=128 fully staged in LDS (4 x 16KB). f32 output.
__global__ __launch_bounds__(256) void k_mfma_p(
    const u16* __restrict__ Ah, const u16* __restrict__ Al,
    const u16* __restrict__ Bh, const u16* __restrict__ Bl,
    float* __restrict__ C) {
  __shared__ __align__(16) u16 sA[2][64 * 128];
  __shared__ __align__(16) u16 sB[2][64 * 128];
  int tid = threadIdx.x;
  int w = tid >> 6, lane = tid & 63;
  int qr = (w >> 1) * 32, qc = (w & 1) * 32;
  int l15 = lane & 15, lhi = lane >> 4;
  int row0 = blockIdx.y * 64, col0 = blockIdx.x * 64;

  f4acc acc[2][2];
#pragma unroll
  for (int i = 0; i < 2; i++)
#pragma unroll
    for (int j = 0; j < 2; j++)
#pragma unroll
      for (int e = 0; e < 4; e++) acc[i][j][e] = 0.f;

#pragma unroll
  for (int hl = 0; hl < 2; hl++) {
    const u16* A = hl ? Al : Ah;
    const u16* B = hl ? Bl : Bh;
#pragma unroll
    for (int p = 0; p < 4; p++) {
      int idx = tid + p * 256;
      int r = idx >> 4, ch = idx & 15;                 // 16 chunks of 16B per 256B row
      int off = r * 256 + ((ch * 16) ^ ((r & 7) << 4));  // XOR bank swizzle
      *(uint4*)((char*)sA[hl] + off) = *(const uint4*)(A + (long)(row0 + r) * D_DIM + ch * 8);
      *(uint4*)((char*)sB[hl] + off) = *(const uint4*)(B + (long)(col0 + r) * D_DIM + ch * 8);
    }
  }
  __syncthreads();

#pragma unroll
  for (int kk = 0; kk < 4; kk++) {
    bfrag ah[2], al[2], bh[2], bl[2];
    int cb = kk * 64 + lhi * 16;
#pragma unroll
    for (int f = 0; f < 2; f++) {
      int ra = qr + f * 16 + l15, rb = qc + f * 16 + l15;
      int oa = ra * 256 + (cb ^ ((ra & 7) << 4));
      int ob = rb * 256 + (cb ^ ((rb & 7) << 4));
      ah[f] = *(const bfrag*)((const char*)sA[0] + oa);
      al[f] = *(const bfrag*)((const char*)sA[1] + oa);
      bh[f] = *(const bfrag*)((const char*)sB[0] + ob);
      bl[f] = *(const bfrag*)((const char*)sB[1] + ob);
    }
#pragma unroll
    for (int i = 0; i < 2; i++)
#pragma unroll
      for (int j = 0; j < 2; j++) {
        acc[i][j] = __builtin_amdgcn_mfma_f32_16x16x32_bf16(ah[i], bh[j], acc[i][j], 0, 0, 0);
        acc[i][j] = __builtin_amdgcn_mfma_f32_16x16x32_bf16(ah[i], bl[j], acc[i][j], 0, 0, 0);
        acc[i][j] = __builtin_amdgcn_mfma_f32_16x16x32_bf16(al[i], bh[j], acc[i][j], 0, 0, 0);
      }
  }

#pragma unroll
  for (int i = 0; i < 2; i++)
#pragma unroll
    for (int j = 0; j < 2; j++) {
      int rbase = row0 + qr + i * 16 + lhi * 4;
      int c = col0 + qc + j * 16 + l15;
#pragma unroll
      for (int e = 0; e < 4; e++)
        C[(long)(rbase + e) * N_DIM + c] = acc[i][j][e];
    }
}

// -------- bf16 MFMA GEMM: C(+)= A[M,K] @ B[N,K]^T, 64x64 tile -----------
// EPI 0: unsafeAtomicAdd into f32 C (split-K). EPI 1: relu(acc)*relu(Xr) -> bf16 C.
// TRI 1: skip tiles strictly above the diagonal.
template <int EPI, int TRI>
__global__ __launch_bounds__(256) void k_mfma_abT(
    const u16* __restrict__ A, const u16* __restrict__ Bm, void* __restrict__ Cv,
    const u16* __restrict__ Xr, int M, int N, int K, int KS,
    long sA, long sB, long sC) {
  int bz = blockIdx.z;
  int batch = bz / KS, ks = bz - batch * KS;
  int row0 = blockIdx.y * 64, col0 = blockIdx.x * 64;
  if (TRI && col0 > row0) return;
  A += (long)batch * sA;
  Bm += (long)batch * sB;
  int kLen = K / KS, k0beg = ks * kLen;

  __shared__ __align__(16) u16 As[64 * 64];
  __shared__ __align__(16) u16 Bs[64 * 64];
  int tid = threadIdx.x;
  int w = tid >> 6, lane = tid & 63;
  int qr = (w >> 1) * 32, qc = (w & 1) * 32;
  int l15 = lane & 15, lhi = lane >> 4;

  f4acc acc[2][2];
#pragma unroll
  for (int i = 0; i < 2; i++)
#pragma unroll
    for (int j = 0; j < 2; j++)
#pragma unroll
      for (int e = 0; e < 4; e++) acc[i][j][e] = 0.f;

  for (int k0 = k0beg; k0 < k0beg + kLen; k0 += 64) {
    __syncthreads();
#pragma unroll
    for (int p = 0; p < 2; p++) {
      int idx = tid + p * 256;
      int r = idx >> 3, c8 = (idx & 7) * 8;           // 8 bf16 = 16B chunk
      uint4 av = *(const uint4*)(A + (long)(row0 + r) * K + k0 + c8);
      uint4 bv = *(const uint4*)(Bm + (long)(col0 + r) * K + k0 + c8);
      int sw = (c8 * 2) ^ ((r & 7) << 4);             // XOR bank swizzle
      *(uint4*)((char*)As + r * 128 + sw) = av;
      *(uint4*)((char*)Bs + r * 128 + sw) = bv;
    }
    __syncthreads();
#pragma unroll
    for (int kk = 0; kk < 2; kk++) {
      bfrag af[2], bf[2];
      int cb = kk * 64 + lhi * 16;                    // byte col within 128B row
#pragma unroll
      for (int f = 0; f < 2; f++) {
        int ra = qr + f * 16 + l15;
        af[f] = *(const bfrag*)((const char*)As + ra * 128 + (cb ^ ((ra & 7) << 4)));
        int rb = qc + f * 16 + l15;
        bf[f] = *(const bfrag*)((const char*)Bs + rb * 128 + (cb ^ ((rb & 7) << 4)));
      }
#pragma unroll
      for (int i = 0; i < 2; i++)
#pragma unroll
        for (int j = 0; j < 2; j++)
          acc[i][j] = __builtin_amdgcn_mfma_f32_16x16x32_bf16(af[i], bf[j], acc[i][j], 0, 0, 0);
    }
  }

#pragma unroll
  for (int i = 0; i < 2; i++)
#pragma unroll
    for (int j = 0; j < 2; j++) {
      int rbase = row0 + qr + i * 16 + lhi * 4;
      int c = col0 + qc + j * 16 + l15;
#pragma unroll
      for (int e = 0; e < 4; e++) {
        long r = rbase + e;
        float v = acc[i][j][e];
        if (EPI == 0) {
          unsafeAtomicAdd((float*)Cv + (long)batch * sC + r * N + c, v);
        } else {
          float xv = bf2f(Xr[r * (long)N + c]);
          ((u16*)Cv)[r * (long)N + c] = f2bf(fmaxf(v, 0.f) * fmaxf(xv, 0.f));
        }
      }
    }
}

// --------------- DPP wave-64 reduction helpers (VALU, no LDS) -----------
template <int CTRL>
__device__ __forceinline__ float dpp_mov(float v) {
  return __int_as_float(
      __builtin_amdgcn_update_dpp(0, __float_as_int(v), CTRL, 0xF, 0xF, true));
}

__device__ __forceinline__ void wave_reduce_sum_max63(float& s, float& m) {
  s += dpp_mov<0x111>(s);  m = fmaxf(m, dpp_mov<0x111>(m));  // row_shr:1
  s += dpp_mov<0x112>(s);  m = fmaxf(m, dpp_mov<0x112>(m));  // row_shr:2
  s += dpp_mov<0x114>(s);  m = fmaxf(m, dpp_mov<0x114>(m));  // row_shr:4
  s += dpp_mov<0x118>(s);  m = fmaxf(m, dpp_mov<0x118>(m));  // row_shr:8
  s += dpp_mov<0x142>(s);  m = fmaxf(m, dpp_mov<0x142>(m));  // row_bcast:15
  s += dpp_mov<0x143>(s);  m = fmaxf(m, dpp_mov<0x143>(m));  // row_bcast:31
}

__device__ __forceinline__ float wave_sum63(float s) {
  s += dpp_mov<0x111>(s);
  s += dpp_mov<0x112>(s);
  s += dpp_mov<0x114>(s);
  s += dpp_mov<0x118>(s);
  s += dpp_mov<0x142>(s);
  s += dpp_mov<0x143>(s);
  return s;
}

// ---------------- sequential x-scan: one block (4 waves) per batch ------
// m201-pattern pipeline: global_load_lds stages row t+2 into a 3-slot LDS
// ring (each wave stages/reads ONLY its own 2KB quarter -> no cross-wave
// hazard on buf). Counted s_waitcnt vmcnt(5): per wave per step the VMEM
// queue is exactly {2 stages, 1 X-store}; 5 = 2(stage t+2)+1(store t-1)+
// 2(stage t+1) newer ops allowed => row t landed, t+1/t+2 in flight.
// Reduce barrier is raw lgkmcnt(0)+s_barrier (no vmcnt(0) drain).
__global__ __launch_bounds__(256) void k_scan(const float* __restrict__ P,
                                              u16* __restrict__ Xb) {
  int b = blockIdx.x;
  int tid = threadIdx.x;
  int wave = tid >> 6;
  int lane = tid & 63;
  __shared__ __align__(16) float buf[3][N_DIM];   // 24KB ring
  __shared__ __align__(16) float red[2][4][2];    // [parity][wave][{sum,max}]

  const float* Prow = P + (long)b * T_SEQ * N_DIM;
  u16* Xrow = Xb + (long)b * T_SEQ * N_DIM;
  const int wq = wave * 512;          // wave's 512-float quarter
  const float* gsrc0 = Prow + wq + lane * 4;

  float x[8];
#pragma unroll
  for (int j = 0; j < 8; j++) x[j] = 0.f;

  // prologue: stage rows 0,1 into slots 0,1; ensure row 0 landed
  stage16(gsrc0, &buf[0][wq]);
  stage16(gsrc0 + 256, &buf[0][wq + 256]);
  stage16(gsrc0 + N_DIM, &buf[1][wq]);
  stage16(gsrc0 + N_DIM + 256, &buf[1][wq + 256]);
  asm volatile("s_waitcnt vmcnt(2)" ::: "memory");
  __builtin_amdgcn_sched_barrier(0);

  int cur = 0;
  for (int t = 0; t < T_SEQ; ++t) {
    int nsl = cur + 2; if (nsl >= 3) nsl -= 3;
    int tp = (t + 2 < T_SEQ) ? t + 2 : T_SEQ - 1;   // clamp; always issue 2 ops
    const float* src = gsrc0 + (long)tp * N_DIM;
    stage16(src, &buf[nsl][wq]);
    stage16(src + 256, &buf[nsl][wq + 256]);
    asm volatile("s_waitcnt vmcnt(5)" ::: "memory");
    __builtin_amdgcn_sched_barrier(0);

    float4 v0 = *(const float4*)&buf[cur][tid * 8];
    float4 v1 = *(const float4*)&buf[cur][tid * 8 + 4];
    float z[8];
    z[0] = 0.97f * x[0] + v0.x;
    z[1] = 0.97f * x[1] + v0.y;
    z[2] = 0.97f * x[2] + v0.z;
    z[3] = 0.97f * x[3] + v0.w;
    z[4] = 0.97f * x[4] + v1.x;
    z[5] = 0.97f * x[5] + v1.y;
    z[6] = 0.97f * x[6] + v1.z;
    z[7] = 0.97f * x[7] + v1.w;
    float s0 = fabsf(z[0]) + fabsf(z[4]);
    float s1 = fabsf(z[1]) + fabsf(z[5]);
    float s2 = fabsf(z[2]) + fabsf(z[6]);
    float s3 = fabsf(z[3]) + fabsf(z[7]);
    float m0 = fmaxf(z[0], z[4]);
    float m1 = fmaxf(z[1], z[5]);
    float m2 = fmaxf(z[2], z[6]);
    float m3 = fmaxf(z[3], z[7]);
    float s = (s0 + s1) + (s2 + s3);
    float m = fmaxf(fmaxf(m0, m1), fmaxf(m2, m3));
    wave_reduce_sum_max63(s, m);
    int par = t & 1;
    if (lane == 63) {
      red[par][wave][0] = s;
      red[par][wave][1] = m;
    }
    asm volatile("s_waitcnt lgkmcnt(0)\n\ts_barrier" ::: "memory");
    float S = (red[par][0][0] + red[par][1][0]) + (red[par][2][0] + red[par][3][0]);
    float M = fmaxf(fmaxf(red[par][0][1], red[par][1][1]),
                    fmaxf(red[par][2][1], red[par][3][1]));
    float inv = 1.f / (S + 1e-6f);
    float thr = 0.02f * M;  // threshold in un-normalized space (scale-invariant)
#pragma unroll
    for (int j = 0; j < 8; j++) x[j] = (z[j] > thr) ? z[j] * inv : 0.f;
    uint4 pk;
    pk.x = (u32)f2bf(x[0]) | ((u32)f2bf(x[1]) << 16);
    pk.y = (u32)f2bf(x[2]) | ((u32)f2bf(x[3]) << 16);
    pk.z = (u32)f2bf(x[4]) | ((u32)f2bf(x[5]) << 16);
    pk.w = (u32)f2bf(x[6]) | ((u32)f2bf(x[7]) << 16);
    *(uint4*)(Xrow + (long)t * N_DIM + tid * 8) = pk;   // 1 VMEM store/wave
    cur = cur + 1; if (cur == 3) cur = 0;
  }
}

// -- a_star[b,t,d] = sum_{s<t} 0.97^(t-s)*S[b,t,s]*Vp[b,s,d], then LN ----
__global__ __launch_bounds__(128) void k_astar_ln(const float* __restrict__ S,
                                                  const float* __restrict__ Vp,
                                                  u16* __restrict__ LnAb) {
  int bx = blockIdx.x;
  int b = bx >> 8, t = bx & 255;
  int d = threadIdx.x;
  int wave = d >> 6, lane = d & 63;
  __shared__ float redS[2], redV[2];
  const float* Sb = S + ((long)b * T_SEQ + t) * T_SEQ;
  const float* Vb = Vp + (long)b * T_SEQ * D_DIM;
  float acc = 0.f;
  float w = 1.f;
  for (int s = t - 1; s >= 0; s--) {
    w *= 0.97f;
    acc += w * Sb[s] * Vb[(long)s * D_DIM + d];
  }
  float s1 = wave_sum63(acc);
  if (lane == 63) redS[wave] = s1;
  __syncthreads();
  float mean = (redS[0] + redS[1]) * (1.f / 128.f);
  float dv = acc - mean;
  float v = wave_sum63(dv * dv);
  if (lane == 63) redV[wave] = v;
  __syncthreads();
  float sd = sqrtf((redV[0] + redV[1]) * (1.f / 127.f));
  LnAb[((long)b * T_SEQ + t) * D_DIM + d] = f2bf(dv / (sd + 1e-6f));
}

// ------------- row layernorm over D=128 (torch ddof=1 semantics) --------
__global__ __launch_bounds__(64) void k_ln(const float* __restrict__ In,
                                           float* __restrict__ Out) {
  long base = (long)blockIdx.x * D_DIM;
  int lane = threadIdx.x;
  float a = In[base + lane];
  float b = In[base + lane + 64];
  float s = a + b;
#pragma unroll
  for (int off = 32; off >= 1; off >>= 1) s += __shfl_xor(s, off);
  float m = s * (1.f / 128.f);
  float da = a - m, db = b - m;
  float v = da * da + db * db;
#pragma unroll
  for (int off = 32; off >= 1; off >>= 1) v += __shfl_xor(v, off);
  float sd = sqrtf(v * (1.f / 127.f));
  float invs = 1.f / (sd + 1e-6f);
  Out[base + lane] = da * invs;
  Out[base + lane + 64] = db * invs;
}

extern "C" void kernel_launch(void* const* d_in, const int* in_sizes, int n_in,
                              void* d_out, int out_size, void* d_ws, size_t ws_size,
                              hipStream_t stream) {
  const float* E = (const float*)d_in[0];     // [128, 2048]
  const float* Dx = (const float*)d_in[1];    // [2048, 128]
  const float* Dy = (const float*)d_in[2];    // [2048, 128]
  const float* emb = (const float*)d_in[3];   // [131072, 128]
  const int* toks = (const int*)d_in[4];      // [8, 256]
  float* out = (float*)d_out;                 // [8, 256, 128]

  char* ws = (char*)d_ws;
  const size_t MB = 1u << 20;
  float* Vp = (float*)(ws + 0 * MB);            // 1 MB    [2048,128] f32
  float* P = (float*)(ws + 1 * MB);             // 16 MB   [2048,2048] f32
  u16* Ytb = (u16*)(ws + 1 * MB);               // 8 MB    reuse (P dead after scan)
  u16* Xb = (u16*)(ws + 17 * MB);               // 8 MB    [2048,2048] bf16
  float* S = (float*)(ws + 25 * MB);            // 2 MB    [8,256,256] f32  } contiguous
  float* U = (float*)(ws + 27 * MB);            // 1 MB    [2048,128] f32   } zero range
  u16* LnAb = (u16*)(ws + 28 * MB);             // 0.5 MB  [2048,128] bf16
  u16* Dyb = (u16*)(ws + 29 * MB);              // 0.5 MB
  u16* Eb = (u16*)(ws + 30 * MB);               // 0.5 MB
  u16* Vph = (u16*)(ws + 31 * MB);              // 0.5 MB
  u16* Vpl = (u16*)(ws + 31 * MB + 512 * 1024); // 0.5 MB
  u16* Dxh = (u16*)(ws + 32 * MB);              // 0.5 MB
  u16* Dxl = (u16*)(ws + 32 * MB + 512 * 1024); // 0.5 MB

  const int R = B_BATCH * T_SEQ;  // 2048

  k_gather<<<R, D_DIM, 0, stream>>>(emb, toks, Vp, Vph, Vpl);
  k_cast<<<256, 256, 0, stream>>>(Dy, Dyb, N_DIM * D_DIM);
  k_cast<<<256, 256, 0, stream>>>(E, Eb, N_DIM * D_DIM);
  k_cast2<<<256, 256, 0, stream>>>(Dx, Dxh, Dxl, N_DIM * D_DIM);
  // P = Vp @ Dx^T via bf16x3 MFMA (~f32 accuracy, feeds the scan)
  k_mfma_p<<<dim3(N_DIM / 64, R / 64), 256, 0, stream>>>(Vph, Vpl, Dxh, Dxl, P);
  // sequential x-scan (LDS-pipelined) -> bf16 X
  k_scan<<<B_BATCH, 256, 0, stream>>>(P, Xb);
  // zero split-K accumulators S+U (3 MB contiguous)
  k_zero<<<768, 256, 0, stream>>>(S, 3L * MB / 16);
  // S = X @ X^T per batch, bf16 MFMA, lower-tri tiles, split-K x4
  k_mfma_abT<0, 1><<<dim3(4, 4, B_BATCH * 4), 256, 0, stream>>>(
      Xb, Xb, S, nullptr, T_SEQ, T_SEQ, N_DIM, 4,
      (long)T_SEQ * N_DIM, (long)T_SEQ * N_DIM, (long)T_SEQ * T_SEQ);
  // a_star = (decay-masked S) @ Vp, fused LN, bf16 out
  k_astar_ln<<<R, D_DIM, 0, stream>>>(S, Vp, LnAb);
  // Yt = relu(LnAb @ Dyb^T) * relu(Xb) -> bf16, MFMA
  k_mfma_abT<1, 0><<<dim3(N_DIM / 64, R / 64, 1), 256, 0, stream>>>(
      LnAb, Dyb, Ytb, Xb, R, N_DIM, D_DIM, 1, 0, 0, 0);
  // U = Ytb @ Eb^T, MFMA split-K x8 (f32 atomics)
  k_mfma_abT<0, 0><<<dim3(D_DIM / 64, R / 64, 8), 256, 0, stream>>>(
      Ytb, Eb, U, nullptr, R, D_DIM, N_DIM, 8, 0, 0, 0);
  k_ln<<<R, 64, 0, stream>>>(U, out);
}